// Round 2
// baseline (3188.868 us; speedup 1.0000x reference)
//
#include <hip/hip_runtime.h>
#include <hip/hip_bf16.h>

#define NN 100000
#define EE 1600000

typedef unsigned short u16;
typedef unsigned int   u32;

__device__ __forceinline__ float b2f(u16 h){ u32 u = ((u32)h) << 16; return __builtin_bit_cast(float, u); }
__device__ __forceinline__ float lo2f(u32 u){ return __builtin_bit_cast(float, u << 16); }
__device__ __forceinline__ float hi2f(u32 u){ return __builtin_bit_cast(float, u & 0xffff0000u); }
__device__ __forceinline__ u16   f2b(float f){ __hip_bfloat16 h = __float2bfloat16(f); return __builtin_bit_cast(u16, h); }
// dual-dtype external load: fm=1 -> float32, fm=0 -> bf16
__device__ __forceinline__ float ldx(const void* p, long i, int fm){
  return fm ? ((const float*)p)[i] : b2f(((const u16*)p)[i]);
}

// ---------------- dtype detection ----------------
// flags[0]: 1 if float inputs are f32, 0 if bf16.
// flags[1]: non_label bool encoding: 1=int32, 3=f32, 2=bf16, 0=u8
__global__ void k_detect(const void* __restrict__ x, const void* __restrict__ nonlab,
                         int* __restrict__ flags){
  const u32* xw = (const u32*)x;
  int bad = 0;
  for (int i = 0; i < 256; ++i){
    u32 w = xw[i];
    u32 lo = w & 0xffffu;
    u32 e = (lo >> 7) & 0xffu;
    if (lo != 0u && (e < 100u || e > 140u)) bad++;
  }
  flags[0] = (bad > 32) ? 1 : 0;
  const u32* wv = (const u32*)nonlab;
  const u16* hv = (const u16*)nonlab;
  bool allint = true, allf32 = true, allbf = true;
  for (int i = 0; i < 64; ++i){
    u32 w = wv[i];
    if (w > 1u) allint = false;
    if (w != 0u && w != 0x3F800000u) allf32 = false;
  }
  for (int i = 0; i < 128; ++i){
    u16 h = hv[i];
    if (h != 0 && h != 0x3F80) allbf = false;
  }
  flags[1] = allint ? 1 : (allf32 ? 3 : (allbf ? 2 : 0));
}

// ---------------- CSR build ----------------
__global__ void k_count(const int* __restrict__ ei, int* __restrict__ cnt){
  int e = blockIdx.x * 256 + threadIdx.x;
  if (e < EE) atomicAdd(&cnt[ei[e]], 1);
}

#define SCAN_C 1024
__global__ void k_scan1(const int* __restrict__ cnt, int* __restrict__ part){
  __shared__ int red[256];
  int b = blockIdx.x, t = threadIdx.x;
  int base = b * SCAN_C + t * 4;
  int s = 0;
  #pragma unroll
  for (int j = 0; j < 4; ++j){ int i = base + j; if (i < NN) s += cnt[i]; }
  red[t] = s; __syncthreads();
  for (int o = 128; o; o >>= 1){ if (t < o) red[t] += red[t + o]; __syncthreads(); }
  if (t == 0) part[b] = red[0];
}
__global__ void k_scan2(int* __restrict__ part, int* __restrict__ rowptr, int nb){
  int acc = 0;
  for (int i = 0; i < nb; ++i){ int v = part[i]; part[i] = acc; acc += v; }
  rowptr[NN] = acc;
}
__global__ void k_scan3(const int* __restrict__ cnt, const int* __restrict__ part,
                        int* __restrict__ rowptr, int* __restrict__ cur){
  __shared__ int lds[256];
  int b = blockIdx.x, t = threadIdx.x;
  int base = b * SCAN_C + t * 4;
  int v[4]; int s = 0;
  #pragma unroll
  for (int j = 0; j < 4; ++j){ int i = base + j; v[j] = (i < NN) ? cnt[i] : 0; s += v[j]; }
  lds[t] = s; __syncthreads();
  for (int o = 1; o < 256; o <<= 1){
    int x = (t >= o) ? lds[t - o] : 0; __syncthreads();
    lds[t] += x; __syncthreads();
  }
  int excl = lds[t] - s + part[b];
  #pragma unroll
  for (int j = 0; j < 4; ++j){
    int i = base + j;
    if (i < NN){ rowptr[i] = excl; cur[i] = excl; excl += v[j]; }
  }
}
__global__ void k_scatter(const int* __restrict__ ei, const void* __restrict__ ew,
                          int* __restrict__ cur, int* __restrict__ ccol,
                          float* __restrict__ cw, const int* __restrict__ flags){
  int e = blockIdx.x * 256 + threadIdx.x;
  if (e >= EE) return;
  int fm = flags[0];
  int r = ei[e], c = ei[EE + e];
  int pos = atomicAdd(&cur[r], 1);
  ccol[pos] = c;
  cw[pos] = ldx(ew, e, fm);
}

// ---------------- SpMM: one wave per row, fp32 reg accumulation ----------------
template<int D, bool EXT>
__global__ __launch_bounds__(256) void k_spmm(const void* __restrict__ in, u16* __restrict__ out,
                       const int* __restrict__ rowptr, const int* __restrict__ ccol,
                       const float* __restrict__ cw, const int* __restrict__ flags){
  int wid  = blockIdx.x * 4 + (threadIdx.x >> 6);
  int lane = threadIdx.x & 63;
  if (wid >= NN) return;
  int fm = EXT ? flags[0] : 0;
  int s = rowptr[wid], e = rowptr[wid + 1];
  float a0 = 0.f, a1 = 0.f, a2 = 0.f;
  for (int j = s; j < e; ++j){
    int c = ccol[j]; float wt = cw[j];
    long base = (long)c * D;
    float v0, v1, v2 = 0.f;
    if (EXT && fm){
      const float* p = (const float*)in + base;
      v0 = p[2 * lane]; v1 = p[2 * lane + 1];
      if (D == 192) v2 = p[128 + lane];
    } else {
      const u16* p = (const u16*)in + base;
      u32 u = *(const u32*)(p + 2 * lane);
      v0 = lo2f(u); v1 = hi2f(u);
      if (D == 192) v2 = b2f(p[128 + lane]);
    }
    a0 = fmaf(wt, v0, a0);
    a1 = fmaf(wt, v1, a1);
    if (D == 192) a2 = fmaf(wt, v2, a2);
  }
  u16* q = out + (long)wid * D;
  *(u32*)(q + 2 * lane) = (u32)f2b(a0) | ((u32)f2b(a1) << 16);
  if (D == 192) q[128 + lane] = f2b(a2);
}

// ---------------- GEMM: A[N,K] internal bf16 @ W[K,FULLD] (+b); W staged to LDS transposed ----------------
template<int K, int DOUT, int SLOTS, int RPT, bool RELU, bool FINAL, int FULLD>
__global__ __launch_bounds__(DOUT*SLOTS) void k_gemm(const u16* __restrict__ A, const void* __restrict__ W,
                       const void* __restrict__ bias, void* __restrict__ outv, int colOff,
                       const int* __restrict__ flags){
  constexpr int KP = K + 6;
  __shared__ u16 Wl[DOUT * KP];
  __shared__ float bl[DOUT];
  int t = threadIdx.x, fm = flags[0];
  int c = t % DOUT, slot = t / DOUT;
  for (int i = t; i < K * DOUT; i += DOUT * SLOTS){
    int k = i / DOUT, cc = i - k * DOUT;
    long wi = (long)k * FULLD + colOff + cc;
    Wl[cc * KP + k] = fm ? f2b(((const float*)W)[wi]) : ((const u16*)W)[wi];
  }
  if (t < DOUT) bl[t] = ldx(bias, colOff + t, fm);
  __syncthreads();
  const u16* wrow = &Wl[c * KP];
  long row0 = (long)blockIdx.x * (SLOTS * RPT) + slot * RPT;
  for (int rr = 0; rr < RPT; ++rr){
    long row = row0 + rr;
    if (row >= NN) return;
    const u16* a = A + row * K;
    float acc = bl[c];
    #pragma unroll 4
    for (int k = 0; k < K; k += 2){
      u32 ua = *(const u32*)(a + k);
      u32 uw = *(const u32*)(wrow + k);
      acc = fmaf(lo2f(ua), lo2f(uw), acc);
      acc = fmaf(hi2f(ua), hi2f(uw), acc);
    }
    if (RELU) acc = fmaxf(acc, 0.f);
    long oi = row * FULLD + colOff + c;
    if (FINAL){
      if (fm) ((float*)outv)[oi] = acc;
      else    ((u16*)outv)[oi] = f2b(acc);
    } else {
      ((u16*)outv)[oi] = f2b(acc);
    }
  }
}

// ---------------- gumbel hard one-hot + where(non_label) ----------------
__global__ __launch_bounds__(256) void k_gumbel(const u16* __restrict__ yenc, const void* __restrict__ ug,
                         const void* __restrict__ ylab, const void* __restrict__ nonlab,
                         const int* __restrict__ flags, u16* __restrict__ y){
  int n = blockIdx.x * 256 + threadIdx.x;
  if (n >= NN) return;
  int fm = flags[0], mode = flags[1];
  bool nl;
  if      (mode == 1) nl = ((const int*)nonlab)[n] != 0;
  else if (mode == 3) nl = ((const float*)nonlab)[n] != 0.f;
  else if (mode == 2) nl = ((const u16*)nonlab)[n] != 0;
  else                nl = ((const unsigned char*)nonlab)[n] != 0;
  long base = (long)n * 32;
  if (nl){
    float best = -1e30f; int bi = 0;
    for (int j = 0; j < 32; ++j){
      float uu = ldx(ug, base + j, fm);
      float g = -logf(-logf(uu + 1e-10f) + 1e-10f);
      float v = b2f(yenc[base + j]) + g;
      if (v > best){ best = v; bi = j; }
    }
    for (int j = 0; j < 32; ++j) y[base + j] = (j == bi) ? (u16)0x3F80 : (u16)0;
  } else {
    for (int j = 0; j < 32; ++j)
      y[base + j] = fm ? f2b(((const float*)ylab)[base + j]) : ((const u16*)ylab)[base + j];
  }
}

// ---------------- encoder mean: colsum of relu(concat(hemb,y) @ W_xy + b); per-wave rows ----------------
__global__ __launch_bounds__(256) void k_encmean(const u16* __restrict__ hemb, const u16* __restrict__ y,
                          const void* __restrict__ W, const void* __restrict__ bias,
                          float* __restrict__ accum, const int* __restrict__ flags){
  constexpr int KP = 166;
  __shared__ u16 Wl[128 * KP];
  __shared__ float bl[128];
  __shared__ float lacc[128];
  int t = threadIdx.x, fm = flags[0];
  int lane = t & 63, w = t >> 6;
  for (int i = t; i < 160 * 128; i += 256)
    Wl[(i & 127) * KP + (i >> 7)] = fm ? f2b(((const float*)W)[i]) : ((const u16*)W)[i];
  if (t < 128){ bl[t] = ldx(bias, t, fm); lacc[t] = 0.f; }
  __syncthreads();
  int c0 = lane, c1 = lane + 64;
  const u16 *w0 = &Wl[c0 * KP], *w1 = &Wl[c1 * KP];
  float cs0 = 0.f, cs1 = 0.f;
  long row0 = (long)blockIdx.x * 64 + w * 16;
  for (int rr = 0; rr < 16; ++rr){
    long row = row0 + rr;
    if (row >= NN) break;               // no syncs below in this loop
    const u16* a  = hemb + row * 128;
    const u16* yr = y + row * 32;
    float acc0 = bl[c0], acc1 = bl[c1];
    for (int k = 0; k < 128; ++k){
      float hv = b2f(a[k]);
      acc0 = fmaf(hv, b2f(w0[k]), acc0);
      acc1 = fmaf(hv, b2f(w1[k]), acc1);
    }
    for (int k = 0; k < 32; ++k){
      float yv = b2f(yr[k]);
      acc0 = fmaf(yv, b2f(w0[128 + k]), acc0);
      acc1 = fmaf(yv, b2f(w1[128 + k]), acc1);
    }
    cs0 += fmaxf(acc0, 0.f);
    cs1 += fmaxf(acc1, 0.f);
  }
  atomicAdd(&lacc[c0], cs0);
  atomicAdd(&lacc[c1], cs1);
  __syncthreads();
  if (t < 128) atomicAdd(&accum[t], lacc[t]);
}

// ---------------- tiny tail: r_graph -> hr -> mu/sigma -> z, plus ||z||^2 ----------------
__global__ void k_z(const float* __restrict__ accum,
                    const void* Whr, const void* bhr, const void* Wrh, const void* brh,
                    const void* Wmu, const void* bmu, const void* Wsig, const void* bsig,
                    const void* zeps, float* __restrict__ zout, const int* __restrict__ flags){
  __shared__ float hm[128], rg[128], hr[128], zl[64];
  int t = threadIdx.x, fm = flags[0];
  hm[t] = accum[t] * (1.0f / 100000.0f);
  __syncthreads();
  { float s = ldx(bhr, t, fm);
    for (int k = 0; k < 128; ++k) s = fmaf(hm[k], ldx(Whr, (long)k * 128 + t, fm), s);
    rg[t] = s; }
  __syncthreads();
  { float s = ldx(brh, t, fm);
    for (int k = 0; k < 128; ++k) s = fmaf(rg[k], ldx(Wrh, (long)k * 128 + t, fm), s);
    hr[t] = fmaxf(s, 0.f); }
  __syncthreads();
  if (t < 64){
    float m = ldx(bmu, t, fm), sv = ldx(bsig, t, fm);
    for (int k = 0; k < 128; ++k){
      float h = hr[k];
      m  = fmaf(h, ldx(Wmu,  (long)k * 64 + t, fm), m);
      sv = fmaf(h, ldx(Wsig, (long)k * 64 + t, fm), sv);
    }
    float sig = 0.1f + 0.9f / (1.f + expf(-sv));
    float z = fmaf(sig, ldx(zeps, t, fm), m);
    zl[t] = z; zout[t] = z;
  }
  __syncthreads();
  if (t == 0){ float ss = 0.f; for (int j = 0; j < 64; ++j) ss += zl[j] * zl[j]; zout[64] = ss; }
}

// ---------------- decoder stage 1: relu(x*dm @ W_xh + b), concat z, row-normalize; per-wave rows ----------------
__global__ __launch_bounds__(256) void k_dec1(const void* __restrict__ x, const void* __restrict__ dm,
                       const void* __restrict__ W, const void* __restrict__ bias,
                       const float* __restrict__ zbuf, u16* __restrict__ out,
                       const int* __restrict__ flags){
  constexpr int KP = 134;
  __shared__ u16 Wl[128 * KP];
  __shared__ float bl[128];
  __shared__ float zl[64];
  __shared__ float zzs_s;
  int t = threadIdx.x, fm = flags[0];
  int lane = t & 63, w = t >> 6;
  for (int i = t; i < 128 * 128; i += 256)
    Wl[(i & 127) * KP + (i >> 7)] = fm ? f2b(((const float*)W)[i]) : ((const u16*)W)[i];
  if (t < 128) bl[t] = ldx(bias, t, fm);
  if (t < 64) zl[t] = zbuf[t];
  if (t == 0) zzs_s = zbuf[64];
  __syncthreads();
  float zz = zzs_s;
  int c0 = lane, c1 = lane + 64;
  const u16 *w0 = &Wl[c0 * KP], *w1 = &Wl[c1 * KP];
  long row0 = (long)blockIdx.x * 64 + w * 16;
  for (int rr = 0; rr < 16; ++rr){
    long row = row0 + rr;
    if (row >= NN) break;               // wave-uniform, no syncs below
    float acc0 = bl[c0], acc1 = bl[c1];
    long xb = row * 128;
    for (int k = 0; k < 128; ++k){
      float xv = ldx(x, xb + k, fm) * ldx(dm, xb + k, fm);
      acc0 = fmaf(xv, b2f(w0[k]), acc0);
      acc1 = fmaf(xv, b2f(w1[k]), acc1);
    }
    float h0 = fmaxf(acc0, 0.f), h1 = fmaxf(acc1, 0.f);
    float ss = h0 * h0 + h1 * h1;
    for (int o = 32; o; o >>= 1) ss += __shfl_xor(ss, o);
    float scale = 1.f / (sqrtf(ss + zz) + 1e-6f);
    u16* q = out + row * 192;
    q[c0] = f2b(h0 * scale);
    q[c1] = f2b(h1 * scale);
    q[128 + lane] = f2b(zl[lane] * scale);
  }
}

extern "C" void kernel_launch(void* const* d_in, const int* in_sizes, int n_in,
                              void* d_out, int out_size, void* d_ws, size_t ws_size,
                              hipStream_t stream){
  const void* x    = d_in[0];
  const void* ylab = d_in[1];
  const int*  ei   = (const int*)d_in[2];
  const void* ew   = d_in[3];
  const void* nonlab = d_in[4];
  const void* dm   = d_in[5];
  const void* ug   = d_in[6];
  const void* zeps = d_in[7];
  const void* Wg1 = d_in[8],  *bg1 = d_in[9];
  const void* Wg2 = d_in[10], *bg2 = d_in[11];
  const void* Wxy = d_in[12], *bxy = d_in[13];
  const void* Whr = d_in[14], *bhr = d_in[15];
  const void* Wrh = d_in[16], *brh = d_in[17];
  const void* Wmu = d_in[18], *bmu = d_in[19];
  const void* Wsg = d_in[20], *bsg = d_in[21];
  const void* Wxh = d_in[22], *bxh = d_in[23];
  const void* Wh2 = d_in[24], *bh2 = d_in[25];
  const void* Why = d_in[26], *bhy = d_in[27];

  char* ws = (char*)d_ws;
  size_t off = 0;
  auto alloc = [&](size_t bytes){ void* p = ws + off; off += (bytes + 511) & ~(size_t)511; return p; };
  int*   flags  = (int*)  alloc(256);
  int*   cntcur = (int*)  alloc((size_t)NN * 4);
  int*   rowptr = (int*)  alloc((size_t)(NN + 1) * 4);
  int*   part   = (int*)  alloc(1024 * 4);
  float* accum  = (float*)alloc(1024 * 4);        // [0:128) colsum, [128:192) z, [192] ||z||^2
  int*   ccol   = (int*)  alloc((size_t)EE * 4);
  float* cw     = (float*)alloc((size_t)EE * 4);
  u16*   B0     = (u16*)  alloc((size_t)NN * 192 * 2);   // ping
  u16*   B1     = (u16*)  alloc((size_t)NN * 192 * 2);   // pong
  // yenc / ybuf live in B0's tail (B0's [N,128] stage uses only the first NN*128 elems)
  u16* yencB = B0 + (size_t)NN * 128;   // [N,32] bf16
  u16* ybuf  = B0 + (size_t)NN * 160;   // [N,32] bf16

  hipMemsetAsync(cntcur, 0, (size_t)NN * 4, stream);
  hipMemsetAsync(accum, 0, 1024 * 4, stream);
  k_detect<<<1, 1, 0, stream>>>(x, nonlab, flags);
  // CSR build (shared by all 4 SpMMs)
  k_count  <<<EE / 256, 256, 0, stream>>>(ei, cntcur);
  k_scan1  <<<98, 256, 0, stream>>>(cntcur, part);
  k_scan2  <<<1, 1, 0, stream>>>(part, rowptr, 98);
  k_scan3  <<<98, 256, 0, stream>>>(cntcur, part, rowptr, cntcur);
  k_scatter<<<EE / 256, 256, 0, stream>>>(ei, ew, cntcur, ccol, cw, flags);
  // pipeline (2-buffer ping-pong)
  k_spmm<128, true ><<<25000, 256, 0, stream>>>(x,  B0, rowptr, ccol, cw, flags);              // S1: x->B0
  k_gemm<128,128,2,32,true ,false,128><<<1563, 256, 0, stream>>>(B0, Wg1, bg1, B1, 0, flags);  // h_emb->B1
  k_spmm<128, false><<<25000, 256, 0, stream>>>(B1, B0, rowptr, ccol, cw, flags);              // S2: B1->B0
  k_gemm<128,32 ,8,8 ,false,false,32 ><<<1563, 256, 0, stream>>>(B0, Wg2, bg2, yencB, 0, flags); // y_encode (bf16)
  k_gumbel<<<(NN + 255) / 256, 256, 0, stream>>>(yencB, ug, ylab, nonlab, flags, ybuf);        // y
  k_encmean<<<1563, 256, 0, stream>>>(B1, ybuf, Wxy, bxy, accum, flags);                        // colsum(h_enc)
  k_z<<<1, 128, 0, stream>>>(accum, Whr, bhr, Wrh, brh, Wmu, bmu, Wsg, bsg, zeps, accum + 128, flags);
  k_dec1<<<1563, 256, 0, stream>>>(x, dm, Wxh, bxh, accum + 128, B1, flags);                   // h [N,192] -> B1
  k_spmm<192, false><<<25000, 256, 0, stream>>>(B1, B0, rowptr, ccol, cw, flags);              // S3: B1->B0
  k_gemm<192,96 ,2,32,true ,false,192><<<1563, 192, 0, stream>>>(B0, Wh2, bh2, B1, 0, flags);  // h2 cols 0..95
  k_gemm<192,96 ,2,32,true ,false,192><<<1563, 192, 0, stream>>>(B0, Wh2, bh2, B1, 96, flags); // h2 cols 96..191
  k_spmm<192, false><<<25000, 256, 0, stream>>>(B1, B0, rowptr, ccol, cw, flags);              // S4: B1->B0
  k_gemm<192,32 ,8,8 ,false,true ,32 ><<<1563, 256, 0, stream>>>(B0, Why, bhy, d_out, 0, flags); // y_pred
}

// Round 4
// 1330.810 us; speedup vs baseline: 2.3962x; 2.3962x over previous
//
#include <hip/hip_runtime.h>
#include <hip/hip_bf16.h>

#define NN 100000
#define EE 1600000

typedef unsigned short u16;
typedef unsigned int   u32;
typedef short short8 __attribute__((ext_vector_type(8)));
typedef float v4f    __attribute__((ext_vector_type(4)));

__device__ __forceinline__ float b2f(u16 h){ u32 u = ((u32)h) << 16; return __builtin_bit_cast(float, u); }
__device__ __forceinline__ float lo2f(u32 u){ return __builtin_bit_cast(float, u << 16); }
__device__ __forceinline__ float hi2f(u32 u){ return __builtin_bit_cast(float, u & 0xffff0000u); }
__device__ __forceinline__ u16   f2b(float f){ __hip_bfloat16 h = __float2bfloat16(f); return __builtin_bit_cast(u16, h); }
__device__ __forceinline__ float ldx(const void* p, long i, int fm){
  return fm ? ((const float*)p)[i] : b2f(((const u16*)p)[i]);
}

// ---------------- dtype detection ----------------
__global__ void k_detect(const void* __restrict__ x, const void* __restrict__ nonlab,
                         int* __restrict__ flags){
  const u32* xw = (const u32*)x;
  int bad = 0;
  for (int i = 0; i < 256; ++i){
    u32 w = xw[i];
    u32 lo = w & 0xffffu;
    u32 e = (lo >> 7) & 0xffu;
    if (lo != 0u && (e < 100u || e > 140u)) bad++;
  }
  flags[0] = (bad > 32) ? 1 : 0;
  const u32* wv = (const u32*)nonlab;
  const u16* hv = (const u16*)nonlab;
  bool allint = true, allf32 = true, allbf = true;
  for (int i = 0; i < 64; ++i){
    u32 w = wv[i];
    if (w > 1u) allint = false;
    if (w != 0u && w != 0x3F800000u) allf32 = false;
  }
  for (int i = 0; i < 128; ++i){
    u16 h = hv[i];
    if (h != 0 && h != 0x3F80) allbf = false;
  }
  flags[1] = allint ? 1 : (allf32 ? 3 : (allbf ? 2 : 0));
}

// ---------------- CSR build ----------------
__global__ void k_count(const int* __restrict__ ei, int* __restrict__ cnt){
  int e = blockIdx.x * 256 + threadIdx.x;
  if (e < EE) atomicAdd(&cnt[ei[e]], 1);
}

#define SCAN_C 1024
__global__ void k_scan1(const int* __restrict__ cnt, int* __restrict__ part){
  __shared__ int red[256];
  int b = blockIdx.x, t = threadIdx.x;
  int base = b * SCAN_C + t * 4;
  int s = 0;
  #pragma unroll
  for (int j = 0; j < 4; ++j){ int i = base + j; if (i < NN) s += cnt[i]; }
  red[t] = s; __syncthreads();
  for (int o = 128; o; o >>= 1){ if (t < o) red[t] += red[t + o]; __syncthreads(); }
  if (t == 0) part[b] = red[0];
}
__global__ void k_scan2(int* __restrict__ part, int* __restrict__ rowptr, int nb){
  int acc = 0;
  for (int i = 0; i < nb; ++i){ int v = part[i]; part[i] = acc; acc += v; }
  rowptr[NN] = acc;
}
__global__ void k_scan3(const int* __restrict__ cnt, const int* __restrict__ part,
                        int* __restrict__ rowptr, int* __restrict__ cur){
  __shared__ int lds[256];
  int b = blockIdx.x, t = threadIdx.x;
  int base = b * SCAN_C + t * 4;
  int v[4]; int s = 0;
  #pragma unroll
  for (int j = 0; j < 4; ++j){ int i = base + j; v[j] = (i < NN) ? cnt[i] : 0; s += v[j]; }
  lds[t] = s; __syncthreads();
  for (int o = 1; o < 256; o <<= 1){
    int x = (t >= o) ? lds[t - o] : 0; __syncthreads();
    lds[t] += x; __syncthreads();
  }
  int excl = lds[t] - s + part[b];
  #pragma unroll
  for (int j = 0; j < 4; ++j){
    int i = base + j;
    if (i < NN){ rowptr[i] = excl; cur[i] = excl; excl += v[j]; }
  }
}
__global__ void k_scatter(const int* __restrict__ ei, const void* __restrict__ ew,
                          int* __restrict__ cur, int* __restrict__ ccol,
                          float* __restrict__ cw, const int* __restrict__ flags){
  int e = blockIdx.x * 256 + threadIdx.x;
  if (e >= EE) return;
  int fm = flags[0];
  int r = ei[e], c = ei[EE + e];
  int pos = atomicAdd(&cur[r], 1);
  ccol[pos] = c;
  cw[pos] = ldx(ew, e, fm);
}

// ---------------- SpMM: one wave per row, fp32 reg accumulation ----------------
template<int D, bool EXT>
__global__ __launch_bounds__(256) void k_spmm(const void* __restrict__ in, u16* __restrict__ out,
                       const int* __restrict__ rowptr, const int* __restrict__ ccol,
                       const float* __restrict__ cw, const int* __restrict__ flags){
  int wid  = blockIdx.x * 4 + (threadIdx.x >> 6);
  int lane = threadIdx.x & 63;
  if (wid >= NN) return;
  int fm = EXT ? flags[0] : 0;
  int s = rowptr[wid], e = rowptr[wid + 1];
  float a0 = 0.f, a1 = 0.f, a2 = 0.f;
  for (int j = s; j < e; ++j){
    int c = ccol[j]; float wt = cw[j];
    long base = (long)c * D;
    float v0, v1, v2 = 0.f;
    if (EXT && fm){
      const float* p = (const float*)in + base;
      v0 = p[2 * lane]; v1 = p[2 * lane + 1];
      if (D == 192) v2 = p[128 + lane];
    } else {
      const u16* p = (const u16*)in + base;
      u32 u = *(const u32*)(p + 2 * lane);
      v0 = lo2f(u); v1 = hi2f(u);
      if (D == 192) v2 = b2f(p[128 + lane]);
    }
    a0 = fmaf(wt, v0, a0);
    a1 = fmaf(wt, v1, a1);
    if (D == 192) a2 = fmaf(wt, v2, a2);
  }
  u16* q = out + (long)wid * D;
  *(u32*)(q + 2 * lane) = (u32)f2b(a0) | ((u32)f2b(a1) << 16);
  if (D == 192) q[128 + lane] = f2b(a2);
}

// ---------------- generic MFMA GEMM ----------------
// A[N,K] @ W[K,DOUT] + b -> out[N,DOUT].  One wave: CT col-tiles (B-frags in regs),
// RTW row-tiles of 16.  Layouts (guide-verified): A[m=lane&15][k=q*8+j],
// B[n=lane&15][k=q*8+j] (gathered transposed), C/D col=lane&15, row=q*4+reg.
// Uses the compiler builtin so all MFMA hazard waitstates are compiler-inserted.
// AMODE: 0 = bf16 buffer A; 1 = x*dm external; 2 = concat(hemb[128], y[32])
// OMODE: 0 = bf16 out; 1 = final out (fm ? f32 : bf16)
template<int K, int DOUT, int CT, int RTW, bool RELU, int AMODE, int OMODE>
__global__ __launch_bounds__(256) void k_mm(const u16* __restrict__ A, const void* __restrict__ A2,
     const void* __restrict__ A3, const void* __restrict__ W, const void* __restrict__ bias,
     void* __restrict__ outv, const int* __restrict__ flags){
  constexpr int STEPS = K / 32;
  constexpr int G = DOUT / (16 * CT);
  constexpr int CHUNKS = 6250 / RTW;      // N = 6250 * 16 exactly
  int wid = blockIdx.x * 4 + (threadIdx.x >> 6);
  if (wid >= G * CHUNKS) return;          // wave-uniform exit, no syncs in kernel
  int g = wid % G; long chunk = wid / G;
  int lane = threadIdx.x & 63, n = lane & 15, q = lane >> 4;
  int colOff = g * CT * 16;
  int fm = flags[0];

  short8 B[CT][STEPS];
  float bv[CT];
  #pragma unroll
  for (int ct = 0; ct < CT; ++ct){
    int col = colOff + ct * 16 + n;
    bv[ct] = ldx(bias, col, fm);
    #pragma unroll
    for (int s = 0; s < STEPS; ++s){
      short8 t;
      if (fm){
        #pragma unroll
        for (int j = 0; j < 8; ++j){
          int k = s * 32 + q * 8 + j;
          t[j] = (short)f2b(((const float*)W)[(long)k * DOUT + col]);
        }
      } else {
        #pragma unroll
        for (int j = 0; j < 8; ++j){
          int k = s * 32 + q * 8 + j;
          t[j] = (short)((const u16*)W)[(long)k * DOUT + col];
        }
      }
      B[ct][s] = t;
    }
  }

  for (int rt = 0; rt < RTW; ++rt){
    long rowbase = (chunk * RTW + rt) * 16;
    long arow = rowbase + n;
    v4f acc[CT] = {};
    #pragma unroll
    for (int s = 0; s < STEPS; ++s){
      short8 a;
      if (AMODE == 0){
        a = *(const short8*)(A + arow * K + s * 32 + q * 8);
      } else if (AMODE == 1){
        long base = arow * 128 + s * 32 + q * 8;
        if (fm){
          const float* xp = (const float*)A2 + base;
          const float* dp = (const float*)A3 + base;
          float4 x0 = *(const float4*)xp, x1 = *(const float4*)(xp + 4);
          float4 d0 = *(const float4*)dp, d1 = *(const float4*)(dp + 4);
          a[0] = (short)f2b(x0.x * d0.x); a[1] = (short)f2b(x0.y * d0.y);
          a[2] = (short)f2b(x0.z * d0.z); a[3] = (short)f2b(x0.w * d0.w);
          a[4] = (short)f2b(x1.x * d1.x); a[5] = (short)f2b(x1.y * d1.y);
          a[6] = (short)f2b(x1.z * d1.z); a[7] = (short)f2b(x1.w * d1.w);
        } else {
          short8 xv = *(const short8*)((const u16*)A2 + base);
          short8 dv = *(const short8*)((const u16*)A3 + base);
          #pragma unroll
          for (int j = 0; j < 8; ++j) a[j] = (short)f2b(b2f((u16)xv[j]) * b2f((u16)dv[j]));
        }
      } else { // AMODE==2: concat(hemb[N,128], y[N,32]), K=160
        if (s < 4) a = *(const short8*)(A + arow * 128 + s * 32 + q * 8);
        else       a = *(const short8*)((const u16*)A2 + arow * 32 + q * 8);
      }
      #pragma unroll
      for (int ct = 0; ct < CT; ++ct)
        acc[ct] = __builtin_amdgcn_mfma_f32_16x16x32_bf16(a, B[ct][s], acc[ct], 0, 0, 0);
    }
    long orow = rowbase + q * 4;
    #pragma unroll
    for (int ct = 0; ct < CT; ++ct){
      int col = colOff + ct * 16 + n;
      #pragma unroll
      for (int r = 0; r < 4; ++r){
        float v = acc[ct][r] + bv[ct];
        if (RELU) v = fmaxf(v, 0.f);
        long oi = (orow + r) * (long)DOUT + col;
        if (OMODE == 1){
          if (fm) ((float*)outv)[oi] = v; else ((u16*)outv)[oi] = f2b(v);
        } else {
          ((u16*)outv)[oi] = f2b(v);
        }
      }
    }
  }
}

// ---------------- gumbel hard one-hot + where(non_label) ----------------
__global__ __launch_bounds__(256) void k_gumbel(const u16* __restrict__ yenc, const void* __restrict__ ug,
                         const void* __restrict__ ylab, const void* __restrict__ nonlab,
                         const int* __restrict__ flags, u16* __restrict__ y){
  int n = blockIdx.x * 256 + threadIdx.x;
  if (n >= NN) return;
  int fm = flags[0], mode = flags[1];
  bool nl;
  if      (mode == 1) nl = ((const int*)nonlab)[n] != 0;
  else if (mode == 3) nl = ((const float*)nonlab)[n] != 0.f;
  else if (mode == 2) nl = ((const u16*)nonlab)[n] != 0;
  else                nl = ((const unsigned char*)nonlab)[n] != 0;
  long base = (long)n * 32;
  if (nl){
    float best = -1e30f; int bi = 0;
    for (int j = 0; j < 32; ++j){
      float uu = ldx(ug, base + j, fm);
      float g = -logf(-logf(uu + 1e-10f) + 1e-10f);
      float v = b2f(yenc[base + j]) + g;
      if (v > best){ best = v; bi = j; }
    }
    for (int j = 0; j < 32; ++j) y[base + j] = (j == bi) ? (u16)0x3F80 : (u16)0;
  } else {
    for (int j = 0; j < 32; ++j)
      y[base + j] = fm ? f2b(((const float*)ylab)[base + j]) : ((const u16*)ylab)[base + j];
  }
}

// ---------------- column-sum of relu'd H [N,128] -> accum[128] ----------------
__global__ __launch_bounds__(256) void k_colsum(const u16* __restrict__ H, float* __restrict__ accum){
  __shared__ float lds[256];
  int t = threadIdx.x, col = t & 127, sub = t >> 7;
  long r0 = (long)blockIdx.x * 400;
  float s = 0.f;
  for (int r = sub; r < 400; r += 2)
    s += b2f(H[(r0 + r) * 128 + col]);
  lds[t] = s; __syncthreads();
  if (t < 128) atomicAdd(&accum[t], lds[t] + lds[t + 128]);
}

// ---------------- tiny tail: r_graph -> hr -> mu/sigma -> z, plus ||z||^2 ----------------
__global__ void k_z(const float* __restrict__ accum,
                    const void* Whr, const void* bhr, const void* Wrh, const void* brh,
                    const void* Wmu, const void* bmu, const void* Wsig, const void* bsig,
                    const void* zeps, float* __restrict__ zout, const int* __restrict__ flags){
  __shared__ float hm[128], rg[128], hr[128], zl[64];
  int t = threadIdx.x, fm = flags[0];
  hm[t] = accum[t] * (1.0f / 100000.0f);
  __syncthreads();
  { float s = ldx(bhr, t, fm);
    for (int k = 0; k < 128; ++k) s = fmaf(hm[k], ldx(Whr, (long)k * 128 + t, fm), s);
    rg[t] = s; }
  __syncthreads();
  { float s = ldx(brh, t, fm);
    for (int k = 0; k < 128; ++k) s = fmaf(rg[k], ldx(Wrh, (long)k * 128 + t, fm), s);
    hr[t] = fmaxf(s, 0.f); }
  __syncthreads();
  if (t < 64){
    float m = ldx(bmu, t, fm), sv = ldx(bsig, t, fm);
    for (int k = 0; k < 128; ++k){
      float h = hr[k];
      m  = fmaf(h, ldx(Wmu,  (long)k * 64 + t, fm), m);
      sv = fmaf(h, ldx(Wsig, (long)k * 64 + t, fm), sv);
    }
    float sig = 0.1f + 0.9f / (1.f + expf(-sv));
    float z = fmaf(sig, ldx(zeps, t, fm), m);
    zl[t] = z; zout[t] = z;
  }
  __syncthreads();
  if (t == 0){ float ss = 0.f; for (int j = 0; j < 64; ++j) ss += zl[j] * zl[j]; zout[64] = ss; }
}

// ---------------- row-normalize: H[N,128] (relu'd) + z -> out[N,192] ----------------
__global__ __launch_bounds__(256) void k_norm(const u16* __restrict__ H, const float* __restrict__ zbuf,
                                              u16* __restrict__ out){
  int wid = blockIdx.x * 4 + (threadIdx.x >> 6);
  int lane = threadIdx.x & 63;
  if (wid >= NN) return;
  u32 hv = *(const u32*)(H + (long)wid * 128 + 2 * lane);
  float h0 = lo2f(hv), h1 = hi2f(hv);
  float ss = h0 * h0 + h1 * h1;
  for (int o = 32; o; o >>= 1) ss += __shfl_xor(ss, o);
  float zz = zbuf[64];
  float zv = zbuf[lane];
  float scale = 1.f / (sqrtf(ss + zz) + 1e-6f);
  u16* q = out + (long)wid * 192;
  *(u32*)(q + 2 * lane) = (u32)f2b(h0 * scale) | ((u32)f2b(h1 * scale) << 16);
  q[128 + lane] = f2b(zv * scale);
}

extern "C" void kernel_launch(void* const* d_in, const int* in_sizes, int n_in,
                              void* d_out, int out_size, void* d_ws, size_t ws_size,
                              hipStream_t stream){
  const void* x    = d_in[0];
  const void* ylab = d_in[1];
  const int*  ei   = (const int*)d_in[2];
  const void* ew   = d_in[3];
  const void* nonlab = d_in[4];
  const void* dm   = d_in[5];
  const void* ug   = d_in[6];
  const void* zeps = d_in[7];
  const void* Wg1 = d_in[8],  *bg1 = d_in[9];
  const void* Wg2 = d_in[10], *bg2 = d_in[11];
  const void* Wxy = d_in[12], *bxy = d_in[13];
  const void* Whr = d_in[14], *bhr = d_in[15];
  const void* Wrh = d_in[16], *brh = d_in[17];
  const void* Wmu = d_in[18], *bmu = d_in[19];
  const void* Wsg = d_in[20], *bsg = d_in[21];
  const void* Wxh = d_in[22], *bxh = d_in[23];
  const void* Wh2 = d_in[24], *bh2 = d_in[25];
  const void* Why = d_in[26], *bhy = d_in[27];

  char* ws = (char*)d_ws;
  size_t off = 0;
  auto alloc = [&](size_t bytes){ void* p = ws + off; off += (bytes + 511) & ~(size_t)511; return p; };
  int*   flags  = (int*)  alloc(256);
  int*   cntcur = (int*)  alloc((size_t)NN * 4);
  int*   rowptr = (int*)  alloc((size_t)(NN + 1) * 4);
  int*   part   = (int*)  alloc(1024 * 4);
  float* accum  = (float*)alloc(1024 * 4);        // [0:128) colsum, [128:192) z, [192] ||z||^2
  int*   ccol   = (int*)  alloc((size_t)EE * 4);
  float* cw     = (float*)alloc((size_t)EE * 4);
  u16*   B0     = (u16*)  alloc((size_t)NN * 192 * 2);
  u16*   B1     = (u16*)  alloc((size_t)NN * 192 * 2);
  // yenc / ybuf live in B1's tail while B1's first [N,128] holds h_emb
  u16* yencB = B1 + (size_t)NN * 128;   // [N,32] bf16
  u16* ybuf  = B1 + (size_t)NN * 160;   // [N,32] bf16

  hipMemsetAsync(cntcur, 0, (size_t)NN * 4, stream);
  hipMemsetAsync(accum, 0, 1024 * 4, stream);
  k_detect<<<1, 1, 0, stream>>>(x, nonlab, flags);
  // CSR build (shared by all 4 SpMMs)
  k_count  <<<EE / 256, 256, 0, stream>>>(ei, cntcur);
  k_scan1  <<<98, 256, 0, stream>>>(cntcur, part);
  k_scan2  <<<1, 1, 0, stream>>>(part, rowptr, 98);
  k_scan3  <<<98, 256, 0, stream>>>(cntcur, part, rowptr, cntcur);
  k_scatter<<<EE / 256, 256, 0, stream>>>(ei, ew, cntcur, ccol, cw, flags);
  // pipeline
  k_spmm<128, true ><<<25000, 256, 0, stream>>>(x,  B0, rowptr, ccol, cw, flags);            // S1: x->B0
  k_mm<128,128,4,10,true ,0,0><<<313, 256, 0, stream>>>(B0, nullptr, nullptr, Wg1, bg1, B1, flags);   // h_emb->B1
  k_spmm<128, false><<<25000, 256, 0, stream>>>(B1, B0, rowptr, ccol, cw, flags);            // S2: B1->B0
  k_mm<128,32 ,2,5 ,false,0,0><<<313, 256, 0, stream>>>(B0, nullptr, nullptr, Wg2, bg2, yencB, flags); // y_encode
  k_gumbel<<<(NN + 255) / 256, 256, 0, stream>>>(yencB, ug, ylab, nonlab, flags, ybuf);      // y
  k_mm<160,128,4,10,true ,2,0><<<313, 256, 0, stream>>>(B1, ybuf, nullptr, Wxy, bxy, B0, flags);      // h_enc->B0
  k_colsum<<<250, 256, 0, stream>>>(B0, accum);                                              // colsum(h_enc)
  k_z<<<1, 128, 0, stream>>>(accum, Whr, bhr, Wrh, brh, Wmu, bmu, Wsg, bsg, zeps, accum + 128, flags);
  k_mm<128,128,4,10,true ,1,0><<<313, 256, 0, stream>>>(nullptr, x, dm, Wxh, bxh, B0, flags);         // H=relu(xd@Wxh)->B0
  k_norm<<<25000, 256, 0, stream>>>(B0, accum + 128, B1);                                    // h [N,192]->B1
  k_spmm<192, false><<<25000, 256, 0, stream>>>(B1, B0, rowptr, ccol, cw, flags);            // S3: B1->B0
  k_mm<192,192,4,10,true ,0,0><<<469, 256, 0, stream>>>(B0, nullptr, nullptr, Wh2, bh2, B1, flags);   // h2->B1
  k_spmm<192, false><<<25000, 256, 0, stream>>>(B1, B0, rowptr, ccol, cw, flags);            // S4: B1->B0
  k_mm<192,32 ,2,5 ,false,0,1><<<313, 256, 0, stream>>>(B0, nullptr, nullptr, Why, bhy, d_out, flags); // y_pred
}

// Round 5
// 1067.904 us; speedup vs baseline: 2.9861x; 1.2462x over previous
//
#include <hip/hip_runtime.h>
#include <hip/hip_bf16.h>

#define NN 100000
#define EE 1600000

typedef unsigned short u16;
typedef unsigned int   u32;
typedef short short8 __attribute__((ext_vector_type(8)));
typedef float v4f    __attribute__((ext_vector_type(4)));

__device__ __forceinline__ float b2f(u16 h){ u32 u = ((u32)h) << 16; return __builtin_bit_cast(float, u); }
__device__ __forceinline__ float lo2f(u32 u){ return __builtin_bit_cast(float, u << 16); }
__device__ __forceinline__ float hi2f(u32 u){ return __builtin_bit_cast(float, u & 0xffff0000u); }
__device__ __forceinline__ u16   f2b(float f){ __hip_bfloat16 h = __float2bfloat16(f); return __builtin_bit_cast(u16, h); }
__device__ __forceinline__ float ldx(const void* p, long i, int fm){
  return fm ? ((const float*)p)[i] : b2f(((const u16*)p)[i]);
}
__device__ __forceinline__ float i2f(int v){ return __builtin_bit_cast(float, v); }

// ---------------- dtype detection (parallel) ----------------
__global__ void k_detect(const void* __restrict__ x, const void* __restrict__ nonlab,
                         int* __restrict__ flags){
  __shared__ int s_bad, s_ni, s_nf, s_nb;
  int t = threadIdx.x;
  if (t == 0){ s_bad = 0; s_ni = 0; s_nf = 0; s_nb = 0; }
  __syncthreads();
  u32 w = ((const u32*)x)[t];
  u32 lo = w & 0xffffu, ex = (lo >> 7) & 0xffu;
  if (lo != 0u && (ex < 100u || ex > 140u)) atomicAdd(&s_bad, 1);
  if (t < 64){
    u32 v = ((const u32*)nonlab)[t];
    if (v > 1u) atomicAdd(&s_ni, 1);
    if (v != 0u && v != 0x3F800000u) atomicAdd(&s_nf, 1);
  }
  if (t < 128){
    u16 h = ((const u16*)nonlab)[t];
    if (h != 0 && h != 0x3F80) atomicAdd(&s_nb, 1);
  }
  __syncthreads();
  if (t == 0){
    flags[0] = (s_bad > 32) ? 1 : 0;
    flags[1] = (s_ni == 0) ? 1 : ((s_nf == 0) ? 3 : ((s_nb == 0) ? 2 : 0));
  }
}

// ---------------- CSR build ----------------
__global__ void k_count(const int* __restrict__ ei, int* __restrict__ cnt){
  int e = blockIdx.x * 256 + threadIdx.x;
  if (e < EE) atomicAdd(&cnt[ei[e]], 1);
}

#define SCAN_C 1024
__global__ void k_scan1(const int* __restrict__ cnt, int* __restrict__ part){
  __shared__ int red[256];
  int b = blockIdx.x, t = threadIdx.x;
  int base = b * SCAN_C + t * 4;
  int s = 0;
  #pragma unroll
  for (int j = 0; j < 4; ++j){ int i = base + j; if (i < NN) s += cnt[i]; }
  red[t] = s; __syncthreads();
  for (int o = 128; o; o >>= 1){ if (t < o) red[t] += red[t + o]; __syncthreads(); }
  if (t == 0) part[b] = red[0];
}
__global__ void k_scan2(int* __restrict__ part, int* __restrict__ rowptr, int nb){
  __shared__ int l[128];
  int t = threadIdx.x;
  int v = (t < nb) ? part[t] : 0;
  l[t] = v; __syncthreads();
  for (int o = 1; o < 128; o <<= 1){
    int x = (t >= o) ? l[t - o] : 0; __syncthreads();
    l[t] += x; __syncthreads();
  }
  if (t < nb) part[t] = l[t] - v;          // exclusive
  if (t == nb - 1) rowptr[NN] = l[t];      // total == EE
}
__global__ void k_scan3(const int* __restrict__ cnt, const int* __restrict__ part,
                        int* __restrict__ rowptr, int* __restrict__ cur){
  __shared__ int lds[256];
  int b = blockIdx.x, t = threadIdx.x;
  int base = b * SCAN_C + t * 4;
  int v[4]; int s = 0;
  #pragma unroll
  for (int j = 0; j < 4; ++j){ int i = base + j; v[j] = (i < NN) ? cnt[i] : 0; s += v[j]; }
  lds[t] = s; __syncthreads();
  for (int o = 1; o < 256; o <<= 1){
    int x = (t >= o) ? lds[t - o] : 0; __syncthreads();
    lds[t] += x; __syncthreads();
  }
  int excl = lds[t] - s + part[b];
  #pragma unroll
  for (int j = 0; j < 4; ++j){
    int i = base + j;
    if (i < NN){ rowptr[i] = excl; cur[i] = excl; excl += v[j]; }
  }
}
__global__ void k_scatter(const int* __restrict__ ei, const void* __restrict__ ew,
                          int* __restrict__ cur, int2* __restrict__ cpk,
                          const int* __restrict__ flags){
  int e = blockIdx.x * 256 + threadIdx.x;
  if (e >= EE) return;
  int fm = flags[0];
  int r = ei[e], c = ei[EE + e];
  int pos = atomicAdd(&cur[r], 1);
  float wv = ldx(ew, e, fm);
  cpk[pos] = make_int2(c, __builtin_bit_cast(int, wv));
}

// ---------------- SpMM: one wave per row, 8 edges in flight ----------------
template<int D, bool EXT>
__global__ __launch_bounds__(256) void k_spmm(const void* __restrict__ in, u16* __restrict__ out,
                       const int* __restrict__ rowptr, const int2* __restrict__ cpk,
                       const int* __restrict__ flags){
  int wid  = blockIdx.x * 4 + (threadIdx.x >> 6);
  int lane = threadIdx.x & 63;
  if (wid >= NN) return;
  int fm = EXT ? flags[0] : 0;
  int s = rowptr[wid], e = rowptr[wid + 1];
  float a0 = 0.f, a1 = 0.f, a2 = 0.f;
  int j = s;
  if (EXT && fm){
    const float* fin = (const float*)in;
    for (; j + 8 <= e; j += 8){
      int2 p[8];
      #pragma unroll
      for (int q = 0; q < 8; ++q) p[q] = cpk[j + q];
      float2 v[8];
      #pragma unroll
      for (int q = 0; q < 8; ++q) v[q] = *(const float2*)(fin + (long)p[q].x * D + 2 * lane);
      #pragma unroll
      for (int q = 0; q < 8; ++q){
        float wt = i2f(p[q].y);
        a0 = fmaf(wt, v[q].x, a0);
        a1 = fmaf(wt, v[q].y, a1);
      }
    }
    for (; j < e; ++j){
      int2 p = cpk[j]; float wt = i2f(p.y);
      float2 v = *(const float2*)(fin + (long)p.x * D + 2 * lane);
      a0 = fmaf(wt, v.x, a0); a1 = fmaf(wt, v.y, a1);
    }
  } else {
    const u16* uin = (const u16*)in;
    for (; j + 8 <= e; j += 8){
      int2 p[8];
      #pragma unroll
      for (int q = 0; q < 8; ++q) p[q] = cpk[j + q];
      u32 u[8]; u16 x2[8];
      #pragma unroll
      for (int q = 0; q < 8; ++q){
        long base = (long)p[q].x * D;
        u[q] = *(const u32*)(uin + base + 2 * lane);
        if (D == 192) x2[q] = uin[base + 128 + lane];
      }
      #pragma unroll
      for (int q = 0; q < 8; ++q){
        float wt = i2f(p[q].y);
        a0 = fmaf(wt, lo2f(u[q]), a0);
        a1 = fmaf(wt, hi2f(u[q]), a1);
        if (D == 192) a2 = fmaf(wt, b2f(x2[q]), a2);
      }
    }
    for (; j < e; ++j){
      int2 p = cpk[j]; float wt = i2f(p.y);
      long base = (long)p.x * D;
      u32 u = *(const u32*)(uin + base + 2 * lane);
      a0 = fmaf(wt, lo2f(u), a0);
      a1 = fmaf(wt, hi2f(u), a1);
      if (D == 192) a2 = fmaf(wt, b2f(uin[base + 128 + lane]), a2);
    }
  }
  u16* q = out + (long)wid * D;
  *(u32*)(q + 2 * lane) = (u32)f2b(a0) | ((u32)f2b(a1) << 16);
  if (D == 192) q[128 + lane] = f2b(a2);
}

// ---------------- generic MFMA GEMM (unchanged from round 4) ----------------
template<int K, int DOUT, int CT, int RTW, bool RELU, int AMODE, int OMODE>
__global__ __launch_bounds__(256) void k_mm(const u16* __restrict__ A, const void* __restrict__ A2,
     const void* __restrict__ A3, const void* __restrict__ W, const void* __restrict__ bias,
     void* __restrict__ outv, const int* __restrict__ flags){
  constexpr int STEPS = K / 32;
  constexpr int G = DOUT / (16 * CT);
  constexpr int CHUNKS = 6250 / RTW;      // N = 6250 * 16 exactly
  int wid = blockIdx.x * 4 + (threadIdx.x >> 6);
  if (wid >= G * CHUNKS) return;          // wave-uniform exit
  int g = wid % G; long chunk = wid / G;
  int lane = threadIdx.x & 63, n = lane & 15, q = lane >> 4;
  int colOff = g * CT * 16;
  int fm = flags[0];

  short8 B[CT][STEPS];
  float bv[CT];
  #pragma unroll
  for (int ct = 0; ct < CT; ++ct){
    int col = colOff + ct * 16 + n;
    bv[ct] = ldx(bias, col, fm);
    #pragma unroll
    for (int s = 0; s < STEPS; ++s){
      short8 t;
      if (fm){
        #pragma unroll
        for (int j = 0; j < 8; ++j){
          int k = s * 32 + q * 8 + j;
          t[j] = (short)f2b(((const float*)W)[(long)k * DOUT + col]);
        }
      } else {
        #pragma unroll
        for (int j = 0; j < 8; ++j){
          int k = s * 32 + q * 8 + j;
          t[j] = (short)((const u16*)W)[(long)k * DOUT + col];
        }
      }
      B[ct][s] = t;
    }
  }

  for (int rt = 0; rt < RTW; ++rt){
    long rowbase = (chunk * RTW + rt) * 16;
    long arow = rowbase + n;
    v4f acc[CT] = {};
    #pragma unroll
    for (int s = 0; s < STEPS; ++s){
      short8 a;
      if (AMODE == 0){
        a = *(const short8*)(A + arow * K + s * 32 + q * 8);
      } else if (AMODE == 1){
        long base = arow * 128 + s * 32 + q * 8;
        if (fm){
          const float* xp = (const float*)A2 + base;
          const float* dp = (const float*)A3 + base;
          float4 x0 = *(const float4*)xp, x1 = *(const float4*)(xp + 4);
          float4 d0 = *(const float4*)dp, d1 = *(const float4*)(dp + 4);
          a[0] = (short)f2b(x0.x * d0.x); a[1] = (short)f2b(x0.y * d0.y);
          a[2] = (short)f2b(x0.z * d0.z); a[3] = (short)f2b(x0.w * d0.w);
          a[4] = (short)f2b(x1.x * d1.x); a[5] = (short)f2b(x1.y * d1.y);
          a[6] = (short)f2b(x1.z * d1.z); a[7] = (short)f2b(x1.w * d1.w);
        } else {
          short8 xv = *(const short8*)((const u16*)A2 + base);
          short8 dv = *(const short8*)((const u16*)A3 + base);
          #pragma unroll
          for (int j = 0; j < 8; ++j) a[j] = (short)f2b(b2f((u16)xv[j]) * b2f((u16)dv[j]));
        }
      } else { // AMODE==2: concat(hemb[N,128], y[N,32]), K=160
        if (s < 4) a = *(const short8*)(A + arow * 128 + s * 32 + q * 8);
        else       a = *(const short8*)((const u16*)A2 + arow * 32 + q * 8);
      }
      #pragma unroll
      for (int ct = 0; ct < CT; ++ct)
        acc[ct] = __builtin_amdgcn_mfma_f32_16x16x32_bf16(a, B[ct][s], acc[ct], 0, 0, 0);
    }
    long orow = rowbase + q * 4;
    #pragma unroll
    for (int ct = 0; ct < CT; ++ct){
      int col = colOff + ct * 16 + n;
      #pragma unroll
      for (int r = 0; r < 4; ++r){
        float v = acc[ct][r] + bv[ct];
        if (RELU) v = fmaxf(v, 0.f);
        long oi = (orow + r) * (long)DOUT + col;
        if (OMODE == 1){
          if (fm) ((float*)outv)[oi] = v; else ((u16*)outv)[oi] = f2b(v);
        } else {
          ((u16*)outv)[oi] = f2b(v);
        }
      }
    }
  }
}

// ---------------- gumbel hard one-hot + where(non_label) ----------------
__global__ __launch_bounds__(256) void k_gumbel(const u16* __restrict__ yenc, const void* __restrict__ ug,
                         const void* __restrict__ ylab, const void* __restrict__ nonlab,
                         const int* __restrict__ flags, u16* __restrict__ y){
  int n = blockIdx.x * 256 + threadIdx.x;
  if (n >= NN) return;
  int fm = flags[0], mode = flags[1];
  bool nl;
  if      (mode == 1) nl = ((const int*)nonlab)[n] != 0;
  else if (mode == 3) nl = ((const float*)nonlab)[n] != 0.f;
  else if (mode == 2) nl = ((const u16*)nonlab)[n] != 0;
  else                nl = ((const unsigned char*)nonlab)[n] != 0;
  long base = (long)n * 32;
  if (nl){
    float best = -1e30f; int bi = 0;
    for (int j = 0; j < 32; ++j){
      float uu = ldx(ug, base + j, fm);
      float g = -logf(-logf(uu + 1e-10f) + 1e-10f);
      float v = b2f(yenc[base + j]) + g;
      if (v > best){ best = v; bi = j; }
    }
    for (int j = 0; j < 32; ++j) y[base + j] = (j == bi) ? (u16)0x3F80 : (u16)0;
  } else {
    for (int j = 0; j < 32; ++j)
      y[base + j] = fm ? f2b(((const float*)ylab)[base + j]) : ((const u16*)ylab)[base + j];
  }
}

// ---------------- column-sum of relu'd H [N,128] -> accum[128] ----------------
__global__ __launch_bounds__(256) void k_colsum(const u16* __restrict__ H, float* __restrict__ accum){
  __shared__ float lds[256];
  int t = threadIdx.x, col = t & 127, sub = t >> 7;
  long r0 = (long)blockIdx.x * 400;
  float s = 0.f;
  for (int r = sub; r < 400; r += 2)
    s += b2f(H[(r0 + r) * 128 + col]);
  lds[t] = s; __syncthreads();
  if (t < 128) atomicAdd(&accum[t], lds[t] + lds[t + 128]);
}

// ---------------- tiny tail: r_graph -> hr -> mu/sigma -> z, plus ||z||^2 ----------------
__global__ void k_z(const float* __restrict__ accum,
                    const void* Whr, const void* bhr, const void* Wrh, const void* brh,
                    const void* Wmu, const void* bmu, const void* Wsig, const void* bsig,
                    const void* zeps, float* __restrict__ zout, const int* __restrict__ flags){
  __shared__ float hm[128], rg[128], hr[128], zl[64];
  int t = threadIdx.x, fm = flags[0];
  hm[t] = accum[t] * (1.0f / 100000.0f);
  __syncthreads();
  { float s = ldx(bhr, t, fm);
    for (int k = 0; k < 128; ++k) s = fmaf(hm[k], ldx(Whr, (long)k * 128 + t, fm), s);
    rg[t] = s; }
  __syncthreads();
  { float s = ldx(brh, t, fm);
    for (int k = 0; k < 128; ++k) s = fmaf(rg[k], ldx(Wrh, (long)k * 128 + t, fm), s);
    hr[t] = fmaxf(s, 0.f); }
  __syncthreads();
  if (t < 64){
    float m = ldx(bmu, t, fm), sv = ldx(bsig, t, fm);
    for (int k = 0; k < 128; ++k){
      float h = hr[k];
      m  = fmaf(h, ldx(Wmu,  (long)k * 64 + t, fm), m);
      sv = fmaf(h, ldx(Wsig, (long)k * 64 + t, fm), sv);
    }
    float sig = 0.1f + 0.9f / (1.f + expf(-sv));
    float z = fmaf(sig, ldx(zeps, t, fm), m);
    zl[t] = z; zout[t] = z;
  }
  __syncthreads();
  if (t == 0){ float ss = 0.f; for (int j = 0; j < 64; ++j) ss += zl[j] * zl[j]; zout[64] = ss; }
}

// ---------------- row-normalize: H[N,128] (relu'd) + z -> out[N,192] ----------------
__global__ __launch_bounds__(256) void k_norm(const u16* __restrict__ H, const float* __restrict__ zbuf,
                                              u16* __restrict__ out){
  int wid = blockIdx.x * 4 + (threadIdx.x >> 6);
  int lane = threadIdx.x & 63;
  if (wid >= NN) return;
  u32 hv = *(const u32*)(H + (long)wid * 128 + 2 * lane);
  float h0 = lo2f(hv), h1 = hi2f(hv);
  float ss = h0 * h0 + h1 * h1;
  for (int o = 32; o; o >>= 1) ss += __shfl_xor(ss, o);
  float zz = zbuf[64];
  float zv = zbuf[lane];
  float scale = 1.f / (sqrtf(ss + zz) + 1e-6f);
  u16* q = out + (long)wid * 192;
  *(u32*)(q + 2 * lane) = (u32)f2b(h0 * scale) | ((u32)f2b(h1 * scale) << 16);
  q[128 + lane] = f2b(zv * scale);
}

extern "C" void kernel_launch(void* const* d_in, const int* in_sizes, int n_in,
                              void* d_out, int out_size, void* d_ws, size_t ws_size,
                              hipStream_t stream){
  const void* x    = d_in[0];
  const void* ylab = d_in[1];
  const int*  ei   = (const int*)d_in[2];
  const void* ew   = d_in[3];
  const void* nonlab = d_in[4];
  const void* dm   = d_in[5];
  const void* ug   = d_in[6];
  const void* zeps = d_in[7];
  const void* Wg1 = d_in[8],  *bg1 = d_in[9];
  const void* Wg2 = d_in[10], *bg2 = d_in[11];
  const void* Wxy = d_in[12], *bxy = d_in[13];
  const void* Whr = d_in[14], *bhr = d_in[15];
  const void* Wrh = d_in[16], *brh = d_in[17];
  const void* Wmu = d_in[18], *bmu = d_in[19];
  const void* Wsg = d_in[20], *bsg = d_in[21];
  const void* Wxh = d_in[22], *bxh = d_in[23];
  const void* Wh2 = d_in[24], *bh2 = d_in[25];
  const void* Why = d_in[26], *bhy = d_in[27];

  char* ws = (char*)d_ws;
  size_t off = 0;
  auto alloc = [&](size_t bytes){ void* p = ws + off; off += (bytes + 511) & ~(size_t)511; return p; };
  int*   flags  = (int*)  alloc(256);
  int*   cntcur = (int*)  alloc((size_t)NN * 4);
  int*   rowptr = (int*)  alloc((size_t)(NN + 1) * 4);
  int*   part   = (int*)  alloc(1024 * 4);
  float* accum  = (float*)alloc(1024 * 4);        // [0:128) colsum, [128:192) z, [192] ||z||^2
  int2*  cpk    = (int2*) alloc((size_t)EE * 8);
  u16*   B0     = (u16*)  alloc((size_t)NN * 192 * 2);
  u16*   B1     = (u16*)  alloc((size_t)NN * 192 * 2);
  // yenc / ybuf live in B1's tail while B1's first [N,128] holds h_emb
  u16* yencB = B1 + (size_t)NN * 128;   // [N,32] bf16
  u16* ybuf  = B1 + (size_t)NN * 160;   // [N,32] bf16

  hipMemsetAsync(cntcur, 0, (size_t)NN * 4, stream);
  hipMemsetAsync(accum, 0, 1024 * 4, stream);
  k_detect<<<1, 256, 0, stream>>>(x, nonlab, flags);
  // CSR build (shared by all 4 SpMMs)
  k_count  <<<EE / 256, 256, 0, stream>>>(ei, cntcur);
  k_scan1  <<<98, 256, 0, stream>>>(cntcur, part);
  k_scan2  <<<1, 128, 0, stream>>>(part, rowptr, 98);
  k_scan3  <<<98, 256, 0, stream>>>(cntcur, part, rowptr, cntcur);
  k_scatter<<<EE / 256, 256, 0, stream>>>(ei, ew, cntcur, cpk, flags);
  // pipeline
  k_spmm<128, true ><<<25000, 256, 0, stream>>>(x,  B0, rowptr, cpk, flags);                 // S1: x->B0
  k_mm<128,128,4,10,true ,0,0><<<313, 256, 0, stream>>>(B0, nullptr, nullptr, Wg1, bg1, B1, flags);   // h_emb->B1
  k_spmm<128, false><<<25000, 256, 0, stream>>>(B1, B0, rowptr, cpk, flags);                 // S2: B1->B0
  k_mm<128,32 ,2,5 ,false,0,0><<<313, 256, 0, stream>>>(B0, nullptr, nullptr, Wg2, bg2, yencB, flags); // y_encode
  k_gumbel<<<(NN + 255) / 256, 256, 0, stream>>>(yencB, ug, ylab, nonlab, flags, ybuf);      // y
  k_mm<160,128,4,10,true ,2,0><<<313, 256, 0, stream>>>(B1, ybuf, nullptr, Wxy, bxy, B0, flags);      // h_enc->B0
  k_colsum<<<250, 256, 0, stream>>>(B0, accum);                                              // colsum(h_enc)
  k_z<<<1, 128, 0, stream>>>(accum, Whr, bhr, Wrh, brh, Wmu, bmu, Wsg, bsg, zeps, accum + 128, flags);
  k_mm<128,128,4,10,true ,1,0><<<313, 256, 0, stream>>>(nullptr, x, dm, Wxh, bxh, B0, flags);         // H=relu(xd@Wxh)->B0
  k_norm<<<25000, 256, 0, stream>>>(B0, accum + 128, B1);                                    // h [N,192]->B1
  k_spmm<192, false><<<25000, 256, 0, stream>>>(B1, B0, rowptr, cpk, flags);                 // S3: B1->B0
  k_mm<192,192,4,10,true ,0,0><<<469, 256, 0, stream>>>(B0, nullptr, nullptr, Wh2, bh2, B1, flags);   // h2->B1
  k_spmm<192, false><<<25000, 256, 0, stream>>>(B1, B0, rowptr, cpk, flags);                 // S4: B1->B0
  k_mm<192,32 ,2,5 ,false,0,1><<<313, 256, 0, stream>>>(B0, nullptr, nullptr, Why, bhy, d_out, flags); // y_pred
}